// Round 6
// baseline (49.467 us; speedup 1.0000x reference)
//
#include <hip/hip_runtime.h>
#include <hip/hip_bf16.h>
#include <math.h>

// Problem constants (fixed by setup_inputs)
#define BB 4
#define NN 48
#define SS 32
#define AA 16
#define AI 8
#define EE 512
#define KK 16
#define NNODE (BB * NN)  // 192
#define NEDGE (BB * EE)  // 2048

// ws layout (byte offsets)
#define WS_CBIN  0         // S*S*AI floats = 32 KB
#define WS_BEAM  32768     // NNODE*KK ints = 12 KB
#define WS_NG    45056     // NNODE floats
#define WS_ACC   46080     // 4 floats (per-batch edge-gold accum)
#define WS_CNT   46208     // 1 int arrival counter
// total < 48 KB

__device__ __forceinline__ bool read_mask(const void* p, int idx, int flag) {
    if (flag == 1) return ((const unsigned char*)p)[idx] != 0;
    if (flag == 2) return ((const float*)p)[idx] != 0.0f;
    return ((const int*)p)[idx] != 0;
}

// Detect bool storage width (uint8 / int32 / f32) from bmask's first 128 bytes.
// bernoulli(0.5) data makes this unambiguous w.h.p. Uniform per wave.
__device__ __forceinline__ int detect_flag(const void* bmask, int lane) {
    unsigned int wrd = ((const unsigned int*)bmask)[lane & 31];
    bool anyF = __any(wrd == 0x3F800000u);
    bool anyG = __any(wrd > 1u);
    return anyF ? 2 : (anyG ? 1 : 0);
}

// ---------------- Kernel 1: node beams + unary gold, cbin table, acc init ----
// blocks 0..47   : 4 waves x 1 node each (node = blk*4 + wid)
// blocks 48..79  : cbin[(s1*S+s2)*AI+a] = imask ? wpb[s1,s2]/icnt[s1,s2] : 0
//                  (block 48 also zeroes the edge accumulators + counter)
__global__ __launch_bounds__(256) void node_kernel(
    const float* __restrict__ unaries,
    const float* __restrict__ behaviors,
    const float* __restrict__ wpu,
    const float* __restrict__ wpb,
    const void* masks, const void* bmask, const void* imask,
    const int* __restrict__ targets,
    float* __restrict__ cbin,
    int* __restrict__ beam,
    float* __restrict__ node_gold,
    float* __restrict__ accE,
    int* __restrict__ counter)
{
    int tid = threadIdx.x;
    int wid = tid >> 6, lane = tid & 63;
    int flag = detect_flag(bmask, lane);

    if (blockIdx.x < 48) {
        int node = blockIdx.x * 4 + wid;        // < 192
        float m = read_mask(masks, node, flag) ? 1.f : 0.f;
        int tgt = targets[node];

        float val = -INFINITY, key = -INFINITY;
        if (lane < SS) {
            int s = lane;
            float u = unaries[node * SS + s];
            const float* bp = behaviors + ((size_t)node * SS + s) * AA;
            float cnt = 0.f, raw = 0.f;
            #pragma unroll
            for (int a = 0; a < AA; ++a) {
                bool mm = read_mask(bmask, s * AA + a, flag);
                cnt += mm ? 1.f : 0.f;
                raw += mm ? bp[a] : 0.f;
            }
            if (cnt == 0.f) cnt = 1.f;
            val = m * (u + wpu[s] * (raw / cnt));   // weighted_unaries
            key = (s == tgt) ? INFINITY : val;      // target -> +inf
        }

        // rank = #states with strictly greater key, ties by lower index
        int rank = 0;
        #pragma unroll
        for (int t = 0; t < SS; ++t) {
            float kt = __shfl(key, t, 64);
            rank += (kt > key) || (kt == key && t < lane);
        }
        bool sel = (lane < SS) && (rank < KK);
        if (sel) beam[node * KK + rank] = lane;

        // log-softmax over the 16 selected values; gold = val[target]
        float mv = sel ? val : -INFINITY;
        #pragma unroll
        for (int off = 32; off >= 1; off >>= 1)
            mv = fmaxf(mv, __shfl_xor(mv, off, 64));
        float se = sel ? expf(val - mv) : 0.f;
        #pragma unroll
        for (int off = 32; off >= 1; off >>= 1)
            se += __shfl_xor(se, off, 64);
        float vt = __shfl(val, tgt, 64);
        if (lane == 0)
            node_gold[node] = (m > 0.f) ? (vt - mv - logf(se)) : 0.f;
    } else {
        if (blockIdx.x == 48 && tid < 5) {
            if (tid < 4) accE[tid] = 0.f;
            else *counter = 0;
        }
        int idx = (blockIdx.x - 48) * 256 + tid;    // [0, 8192)
        int p = idx >> 3;                           // (s1*S+s2)
        float cnt = 0.f;
        #pragma unroll
        for (int a = 0; a < AI; ++a)
            cnt += read_mask(imask, p * AI + a, flag) ? 1.f : 0.f;
        if (cnt == 0.f) cnt = 1.f;
        bool mm = read_mask(imask, idx, flag);
        cbin[idx] = mm ? (wpb[p] / cnt) : 0.f;
    }
}

// ---------------- Kernel 2: edge gather + logsumexp + atomic tail ------------
// 2048 blocks x 256 threads; thread = one beam pair (max TLP — R4 lesson).
// Last-arriving block computes the final nll (no threadfence — R1 lesson).
__global__ __launch_bounds__(256) void edge_kernel(
    const float* __restrict__ interactions,
    const int* __restrict__ edges,
    const void* binmask, const void* bmask, const void* masks,
    const float* __restrict__ cbin,
    const int* __restrict__ beam,
    const float* __restrict__ node_gold,
    float* __restrict__ accE,
    int* __restrict__ counter,
    float* __restrict__ out)
{
    int be = blockIdx.x;            // be = b*E + e
    int b = be >> 9;                // /EE
    int tid = threadIdx.x;
    int wid = tid >> 6, lane = tid & 63;

    int n1 = edges[be * 2 + 0];
    int n2 = edges[be * 2 + 1];

    int i = tid >> 4, j = tid & 15;
    int s1 = beam[(b * NN + n1) * KK + i];
    int s2 = beam[(b * NN + n2) * KK + j];
    int p = s1 * SS + s2;

    size_t base = (((size_t)(b * NN + n1) * NN + n2) * (SS * SS) + p) * AI;
    float4 x0 = *(const float4*)(interactions + base);
    float4 x1 = *(const float4*)(interactions + base + 4);
    float4 c0 = *(const float4*)(cbin + p * AI);
    float4 c1 = *(const float4*)(cbin + p * AI + 4);
    float phi = x0.x * c0.x + x0.y * c0.y + x0.z * c0.z + x0.w * c0.w
              + x1.x * c1.x + x1.y * c1.y + x1.z * c1.z + x1.w * c1.w;

    __shared__ float sred[4];
    __shared__ int s_last;
    float v = phi;
    #pragma unroll
    for (int off = 32; off >= 1; off >>= 1)
        v = fmaxf(v, __shfl_xor(v, off, 64));
    if (lane == 0) sred[wid] = v;
    __syncthreads();
    float mx = fmaxf(fmaxf(sred[0], sred[1]), fmaxf(sred[2], sred[3]));
    __syncthreads();
    float e = expf(phi - mx);
    #pragma unroll
    for (int off = 32; off >= 1; off >>= 1)
        e += __shfl_xor(e, off, 64);
    if (lane == 0) sred[wid] = e;
    __syncthreads();
    if (tid == 0) {
        int flag = detect_flag(bmask, lane);
        float s = sred[0] + sred[1] + sred[2] + sred[3];
        float gold = phi - mx - logf(s);        // thread 0 holds phi[0][0]
        bool bm = read_mask(binmask, be, flag);
        atomicAdd(&accE[b], bm ? gold : 0.f);   // device-scope, coherent path
        // Order the accumulate before the arrival tick: wait for the atomic
        // to reach the coherent point. (NOT __threadfence — R1 lesson.)
        asm volatile("s_waitcnt vmcnt(0)" ::: "memory");
        int prev = atomicAdd(counter, 1);
        s_last = (prev == NEDGE - 1) ? 1 : 0;
    }
    __syncthreads();

    if (s_last) {
        // All other blocks' accE adds completed (each waited vmcnt(0) before
        // its counter tick). node_gold/masks come from the previous dispatch.
        int bb = wid;                           // wave w handles batch b=w
        int flag = detect_flag(bmask, lane);
        float sum = 0.f, cnt = 0.f;
        if (lane < NN) {
            sum = node_gold[bb * NN + lane];
            cnt = read_mask(masks, bb * NN + lane, flag) ? 1.f : 0.f;
        }
        #pragma unroll
        for (int off = 32; off >= 1; off >>= 1) {
            sum += __shfl_xor(sum, off, 64);
            cnt += __shfl_xor(cnt, off, 64);
        }
        __syncthreads();                        // sred reuse
        if (lane == 0) {
            float etot = atomicAdd(&accE[bb], 0.f);  // coherent read
            sred[bb] = (sum + etot) / cnt;
        }
        __syncthreads();
        if (tid == 0)
            out[0] = -(sred[0] + sred[1] + sred[2] + sred[3]) * (1.f / BB);
    }
}

extern "C" void kernel_launch(void* const* d_in, const int* in_sizes, int n_in,
                              void* d_out, int out_size, void* d_ws, size_t ws_size,
                              hipStream_t stream) {
    const float* unaries      = (const float*)d_in[0];
    const float* behaviors    = (const float*)d_in[1];
    const float* interactions = (const float*)d_in[2];
    const float* wpu          = (const float*)d_in[3];
    const float* wpb          = (const float*)d_in[4];
    const void*  masks        = d_in[5];
    const void*  bmask        = d_in[6];
    const void*  imask        = d_in[7];
    const int*   edges        = (const int*)d_in[8];
    const void*  binmask      = d_in[9];
    const int*   targets      = (const int*)d_in[10];
    float* out = (float*)d_out;

    char* ws = (char*)d_ws;
    float* cbin      = (float*)(ws + WS_CBIN);
    int*   beamp     = (int*)(ws + WS_BEAM);
    float* node_gold = (float*)(ws + WS_NG);
    float* accE      = (float*)(ws + WS_ACC);
    int*   counter   = (int*)(ws + WS_CNT);

    node_kernel<<<80, 256, 0, stream>>>(unaries, behaviors, wpu, wpb,
                                        masks, bmask, imask, targets,
                                        cbin, beamp, node_gold, accE, counter);
    edge_kernel<<<NEDGE, 256, 0, stream>>>(interactions, edges, binmask, bmask,
                                           masks, cbin, beamp, node_gold,
                                           accE, counter, out);
}

// Round 7
// 20.247 us; speedup vs baseline: 2.4432x; 2.4432x over previous
//
#include <hip/hip_runtime.h>
#include <hip/hip_bf16.h>
#include <math.h>

// Problem constants (fixed by setup_inputs)
#define BB 4
#define NN 48
#define SS 32
#define AA 16
#define AI 8
#define EE 512
#define KK 16
#define NNODE (BB * NN)  // 192
#define NEDGE (BB * EE)  // 2048

// ws layout (byte offsets)
#define WS_CBIN  0         // S*S*AI floats = 32 KB
#define WS_BEAM  32768     // NNODE*KK ints = 12 KB
#define WS_NG    45056     // NNODE floats
#define WS_EG    46080     // NEDGE floats
// total < 56 KB

__device__ __forceinline__ bool read_mask(const void* p, int idx, int flag) {
    if (flag == 1) return ((const unsigned char*)p)[idx] != 0;
    if (flag == 2) return ((const float*)p)[idx] != 0.0f;
    return ((const int*)p)[idx] != 0;
}

// Detect bool storage width (uint8 / int32 / f32) from bmask's first 128 bytes.
// bernoulli(0.5) data makes this unambiguous w.h.p. Uniform per wave.
__device__ __forceinline__ int detect_flag(const void* bmask, int lane) {
    unsigned int wrd = ((const unsigned int*)bmask)[lane & 31];
    bool anyF = __any(wrd == 0x3F800000u);
    bool anyG = __any(wrd > 1u);
    return anyF ? 2 : (anyG ? 1 : 0);
}

// ---------------- Kernel 1: node beams + unary gold, and cbin table ----------
// blocks 0..47  : 4 waves x 1 node each (node = blk*4 + wid)
// blocks 48..51 : cbin: thread <-> p=(s1,s2); vectorized row decode + stores
__global__ __launch_bounds__(256) void node_kernel(
    const float* __restrict__ unaries,
    const float* __restrict__ behaviors,
    const float* __restrict__ wpu,
    const float* __restrict__ wpb,
    const void* masks, const void* bmask, const void* imask,
    const int* __restrict__ targets,
    float* __restrict__ cbin,
    int* __restrict__ beam,
    float* __restrict__ node_gold)
{
    int tid = threadIdx.x;
    int wid = tid >> 6, lane = tid & 63;
    int flag = detect_flag(bmask, lane);

    if (blockIdx.x < 48) {
        int node = blockIdx.x * 4 + wid;        // < 192
        float m = read_mask(masks, node, flag) ? 1.f : 0.f;
        int tgt = targets[node];

        float val = -INFINITY, key = -INFINITY;
        if (lane < SS) {
            int s = lane;
            float u = unaries[node * SS + s];

            // vectorized behavior row (16 floats = 4 x float4)
            const float4* bp4 = (const float4*)(behaviors + ((size_t)node * SS + s) * AA);
            float4 b0 = bp4[0], b1 = bp4[1], b2 = bp4[2], b3 = bp4[3];
            float bv[16] = {b0.x,b0.y,b0.z,b0.w, b1.x,b1.y,b1.z,b1.w,
                            b2.x,b2.y,b2.z,b2.w, b3.x,b3.y,b3.z,b3.w};

            // vectorized mask row decode (wave-uniform branch on flag)
            float bmv[16];
            if (flag == 1) {
                uint4 v = *(const uint4*)((const unsigned char*)bmask + s * 16);
                unsigned int w4[4] = {v.x, v.y, v.z, v.w};
                #pragma unroll
                for (int k = 0; k < 16; ++k)
                    bmv[k] = ((w4[k >> 2] >> ((k & 3) * 8)) & 255u) ? 1.f : 0.f;
            } else if (flag == 0) {
                const uint4* ip = (const uint4*)((const int*)bmask + s * 16);
                #pragma unroll
                for (int r = 0; r < 4; ++r) {
                    uint4 v = ip[r];
                    bmv[r*4+0] = v.x ? 1.f : 0.f; bmv[r*4+1] = v.y ? 1.f : 0.f;
                    bmv[r*4+2] = v.z ? 1.f : 0.f; bmv[r*4+3] = v.w ? 1.f : 0.f;
                }
            } else {
                const float4* fp = (const float4*)((const float*)bmask + s * 16);
                #pragma unroll
                for (int r = 0; r < 4; ++r) {
                    float4 v = fp[r];
                    bmv[r*4+0] = v.x != 0.f ? 1.f : 0.f; bmv[r*4+1] = v.y != 0.f ? 1.f : 0.f;
                    bmv[r*4+2] = v.z != 0.f ? 1.f : 0.f; bmv[r*4+3] = v.w != 0.f ? 1.f : 0.f;
                }
            }

            float cnt = 0.f, raw = 0.f;
            #pragma unroll
            for (int k = 0; k < 16; ++k) { cnt += bmv[k]; raw += bmv[k] * bv[k]; }
            if (cnt == 0.f) cnt = 1.f;
            val = m * (u + wpu[s] * (raw / cnt));   // weighted_unaries
            key = (s == tgt) ? INFINITY : val;      // target -> +inf
        }

        // rank = #states with strictly greater key, ties by lower index
        int rank = 0;
        #pragma unroll
        for (int t = 0; t < SS; ++t) {
            float kt = __shfl(key, t, 64);
            rank += (kt > key) || (kt == key && t < lane);
        }
        bool sel = (lane < SS) && (rank < KK);

        // Beam slot: target -> 0; other selected states sorted by state index
        // (slots 1..15). Valid because only slot 0 is semantically special;
        // the logsumexp terms are set-invariant. Sorted order improves the
        // edge kernel's gather locality (ascending addresses per 16-group).
        bool sel_nt = sel && (lane != tgt);
        unsigned long long bal = __ballot(sel_nt);
        if (sel) {
            int slot = (lane == tgt) ? 0
                       : 1 + __popcll(bal & ((1ull << lane) - 1ull));
            beam[node * KK + slot] = lane;
        }

        // log-softmax over the 16 selected values; gold = val[target]
        float mv = sel ? val : -INFINITY;
        #pragma unroll
        for (int off = 32; off >= 1; off >>= 1)
            mv = fmaxf(mv, __shfl_xor(mv, off, 64));
        float se = sel ? expf(val - mv) : 0.f;
        #pragma unroll
        for (int off = 32; off >= 1; off >>= 1)
            se += __shfl_xor(se, off, 64);
        float vt = __shfl(val, tgt, 64);
        if (lane == 0)
            node_gold[node] = (m > 0.f) ? (vt - mv - logf(se)) : 0.f;
    } else {
        // cbin: one thread per p = (s1*S+s2); 1024 p over 4 blocks
        int p = (blockIdx.x - 48) * 256 + tid;      // [0, 1024)
        float imv[8];
        if (flag == 1) {
            uint2 v = *(const uint2*)((const unsigned char*)imask + p * 8);
            unsigned int w2[2] = {v.x, v.y};
            #pragma unroll
            for (int k = 0; k < 8; ++k)
                imv[k] = ((w2[k >> 2] >> ((k & 3) * 8)) & 255u) ? 1.f : 0.f;
        } else if (flag == 0) {
            const uint4* ip = (const uint4*)((const int*)imask + p * 8);
            uint4 v0 = ip[0], v1 = ip[1];
            imv[0]=v0.x?1.f:0.f; imv[1]=v0.y?1.f:0.f; imv[2]=v0.z?1.f:0.f; imv[3]=v0.w?1.f:0.f;
            imv[4]=v1.x?1.f:0.f; imv[5]=v1.y?1.f:0.f; imv[6]=v1.z?1.f:0.f; imv[7]=v1.w?1.f:0.f;
        } else {
            const float4* fp = (const float4*)((const float*)imask + p * 8);
            float4 v0 = fp[0], v1 = fp[1];
            imv[0]=v0.x!=0.f?1.f:0.f; imv[1]=v0.y!=0.f?1.f:0.f; imv[2]=v0.z!=0.f?1.f:0.f; imv[3]=v0.w!=0.f?1.f:0.f;
            imv[4]=v1.x!=0.f?1.f:0.f; imv[5]=v1.y!=0.f?1.f:0.f; imv[6]=v1.z!=0.f?1.f:0.f; imv[7]=v1.w!=0.f?1.f:0.f;
        }
        float cnt = imv[0]+imv[1]+imv[2]+imv[3]+imv[4]+imv[5]+imv[6]+imv[7];
        if (cnt == 0.f) cnt = 1.f;
        float w = wpb[p] / cnt;
        float4 o0 = make_float4(imv[0]*w, imv[1]*w, imv[2]*w, imv[3]*w);
        float4 o1 = make_float4(imv[4]*w, imv[5]*w, imv[6]*w, imv[7]*w);
        *(float4*)(cbin + p * AI)     = o0;
        *(float4*)(cbin + p * AI + 4) = o1;
    }
}

// ---------------- Kernel 2: edge gather + 1-barrier logsumexp ----------------
// 1024 blocks x 512 threads = 2 edges/block; thread = one beam pair (R4 lesson:
// keep full TLP). Per-wave logsumexp partials -> single barrier -> combine.
__global__ __launch_bounds__(512) void edge_kernel(
    const float* __restrict__ interactions,
    const int* __restrict__ edges,
    const void* binmask, const void* bmask,
    const float* __restrict__ cbin,
    const int* __restrict__ beam,
    float* __restrict__ edge_gold)
{
    int tid = threadIdx.x;
    int le = tid >> 8;              // local edge 0/1
    int t  = tid & 255;             // thread within edge
    int wid = tid >> 6;             // 0..7
    int lane = tid & 63;
    int be = (blockIdx.x << 1) + le;
    int b = be >> 9;                // /EE

    int2 e2 = ((const int2*)edges)[be];
    int n1 = e2.x, n2 = e2.y;

    int i = t >> 4, j = t & 15;
    int s1 = beam[(b * NN + n1) * KK + i];
    int s2 = beam[(b * NN + n2) * KK + j];
    int p = s1 * SS + s2;

    size_t base = (((size_t)(b * NN + n1) * NN + n2) * (SS * SS) + p) * AI;
    float4 x0 = *(const float4*)(interactions + base);
    float4 x1 = *(const float4*)(interactions + base + 4);
    float4 c0 = *(const float4*)(cbin + p * AI);
    float4 c1 = *(const float4*)(cbin + p * AI + 4);
    float phi = x0.x * c0.x + x0.y * c0.y + x0.z * c0.z + x0.w * c0.w
              + x1.x * c1.x + x1.y * c1.y + x1.z * c1.z + x1.w * c1.w;

    // per-wave partials: max and sum(exp(phi - max))
    float mw = phi;
    #pragma unroll
    for (int off = 32; off >= 1; off >>= 1)
        mw = fmaxf(mw, __shfl_xor(mw, off, 64));
    float ew = expf(phi - mw);
    #pragma unroll
    for (int off = 32; off >= 1; off >>= 1)
        ew += __shfl_xor(ew, off, 64);

    __shared__ float2 sred[8];
    if (lane == 0) sred[wid] = make_float2(mw, ew);
    __syncthreads();

    if (t == 0) {                   // tid 0 and tid 256; each holds phi[0][0]
        int w0 = le << 2;
        float2 p0 = sred[w0], p1 = sred[w0+1], p2 = sred[w0+2], p3 = sred[w0+3];
        float M = fmaxf(fmaxf(p0.x, p1.x), fmaxf(p2.x, p3.x));
        float S = p0.y * expf(p0.x - M) + p1.y * expf(p1.x - M)
                + p2.y * expf(p2.x - M) + p3.y * expf(p3.x - M);
        float gold = phi - M - logf(S);
        int flag = detect_flag(bmask, lane);
        bool bm = read_mask(binmask, be, flag);
        edge_gold[be] = bm ? gold : 0.f;
    }
}

// ---------------- Kernel 3: final reduction -> nll ---------------------------
__global__ __launch_bounds__(256) void final_kernel(
    const void* masks, const void* bmask,
    const float* __restrict__ node_gold,
    const float* __restrict__ edge_gold,
    float* __restrict__ out)
{
    int tid = threadIdx.x;          // 4 waves, wave w = batch b
    int b = tid >> 6;
    int lane = tid & 63;
    int flag = detect_flag(bmask, lane);

    float sum = 0.f, cnt = 0.f;
    if (lane < NN) {
        sum += node_gold[b * NN + lane];
        cnt += read_mask(masks, b * NN + lane, flag) ? 1.f : 0.f;
    }
    for (int e = lane; e < EE; e += 64)
        sum += edge_gold[b * EE + e];

    #pragma unroll
    for (int off = 32; off >= 1; off >>= 1) {
        sum += __shfl_xor(sum, off, 64);
        cnt += __shfl_xor(cnt, off, 64);
    }
    __shared__ float sp[4];
    if (lane == 0) sp[b] = sum / cnt;
    __syncthreads();
    if (tid == 0)
        out[0] = -(sp[0] + sp[1] + sp[2] + sp[3]) * (1.f / BB);
}

extern "C" void kernel_launch(void* const* d_in, const int* in_sizes, int n_in,
                              void* d_out, int out_size, void* d_ws, size_t ws_size,
                              hipStream_t stream) {
    const float* unaries      = (const float*)d_in[0];
    const float* behaviors    = (const float*)d_in[1];
    const float* interactions = (const float*)d_in[2];
    const float* wpu          = (const float*)d_in[3];
    const float* wpb          = (const float*)d_in[4];
    const void*  masks        = d_in[5];
    const void*  bmask        = d_in[6];
    const void*  imask        = d_in[7];
    const int*   edges        = (const int*)d_in[8];
    const void*  binmask      = d_in[9];
    const int*   targets      = (const int*)d_in[10];
    float* out = (float*)d_out;

    char* ws = (char*)d_ws;
    float* cbin      = (float*)(ws + WS_CBIN);
    int*   beamp     = (int*)(ws + WS_BEAM);
    float* node_gold = (float*)(ws + WS_NG);
    float* edge_gold = (float*)(ws + WS_EG);

    node_kernel<<<52, 256, 0, stream>>>(unaries, behaviors, wpu, wpb,
                                        masks, bmask, imask, targets,
                                        cbin, beamp, node_gold);
    edge_kernel<<<NEDGE / 2, 512, 0, stream>>>(interactions, edges, binmask,
                                               bmask, cbin, beamp, edge_gold);
    final_kernel<<<1, 256, 0, stream>>>(masks, bmask, node_gold, edge_gold, out);
}

// Round 8
// 17.594 us; speedup vs baseline: 2.8115x; 1.1508x over previous
//
#include <hip/hip_runtime.h>
#include <hip/hip_bf16.h>
#include <math.h>

// Problem constants (fixed by setup_inputs)
#define BB 4
#define NN 48
#define SS 32
#define AA 16
#define AI 8
#define EE 512
#define KK 16
#define NNODE (BB * NN)  // 192
#define NEDGE (BB * EE)  // 2048

// ws layout (byte offsets)
#define WS_NG    0         // NNODE floats (node gold)
#define WS_EG    1024      // NEDGE floats (edge gold)

__device__ __forceinline__ bool read_mask(const void* p, int idx, int flag) {
    if (flag == 1) return ((const unsigned char*)p)[idx] != 0;
    if (flag == 2) return ((const float*)p)[idx] != 0.0f;
    return ((const int*)p)[idx] != 0;
}

// Detect bool storage width (uint8 / int32 / f32) from bmask's first 128 bytes.
// bernoulli(0.5) data makes this unambiguous w.h.p. Uniform per wave.
__device__ __forceinline__ int detect_flag(const void* bmask, int lane) {
    unsigned int wrd = ((const unsigned int*)bmask)[lane & 31];
    bool anyF = __any(wrd == 0x3F800000u);
    bool anyG = __any(wrd > 1u);
    return anyF ? 2 : (anyG ? 1 : 0);
}

// Full-wave node routine: lanes 0..31 own state s=lane. Computes weighted
// unaries, stable top-16 rank select (target -> slot 0, others sorted by
// state index for gather locality), optional LDS beam write + gold write.
__device__ __forceinline__ void node_beam(
    int node, int lane, int flag,
    const float* __restrict__ unaries, const float* __restrict__ behaviors,
    const void* masks, const int* __restrict__ targets,
    const float* __restrict__ wpu, const void* bmask,
    int* beam16, float* gold_out)
{
    float m = read_mask(masks, node, flag) ? 1.f : 0.f;
    int tgt = targets[node];

    float val = -INFINITY, key = -INFINITY;
    if (lane < SS) {
        int s = lane;
        float u = unaries[node * SS + s];

        // vectorized behavior row (16 floats = 4 x float4)
        const float4* bp4 = (const float4*)(behaviors + ((size_t)node * SS + s) * AA);
        float4 b0 = bp4[0], b1 = bp4[1], b2 = bp4[2], b3 = bp4[3];
        float bv[16] = {b0.x,b0.y,b0.z,b0.w, b1.x,b1.y,b1.z,b1.w,
                        b2.x,b2.y,b2.z,b2.w, b3.x,b3.y,b3.z,b3.w};

        // vectorized mask row decode (wave-uniform branch on flag)
        float bmv[16];
        if (flag == 1) {
            uint4 v = *(const uint4*)((const unsigned char*)bmask + s * 16);
            unsigned int w4[4] = {v.x, v.y, v.z, v.w};
            #pragma unroll
            for (int k = 0; k < 16; ++k)
                bmv[k] = ((w4[k >> 2] >> ((k & 3) * 8)) & 255u) ? 1.f : 0.f;
        } else if (flag == 0) {
            const uint4* ip = (const uint4*)((const int*)bmask + s * 16);
            #pragma unroll
            for (int r = 0; r < 4; ++r) {
                uint4 v = ip[r];
                bmv[r*4+0] = v.x ? 1.f : 0.f; bmv[r*4+1] = v.y ? 1.f : 0.f;
                bmv[r*4+2] = v.z ? 1.f : 0.f; bmv[r*4+3] = v.w ? 1.f : 0.f;
            }
        } else {
            const float4* fp = (const float4*)((const float*)bmask + s * 16);
            #pragma unroll
            for (int r = 0; r < 4; ++r) {
                float4 v = fp[r];
                bmv[r*4+0] = v.x != 0.f ? 1.f : 0.f; bmv[r*4+1] = v.y != 0.f ? 1.f : 0.f;
                bmv[r*4+2] = v.z != 0.f ? 1.f : 0.f; bmv[r*4+3] = v.w != 0.f ? 1.f : 0.f;
            }
        }

        float cnt = 0.f, raw = 0.f;
        #pragma unroll
        for (int k = 0; k < 16; ++k) { cnt += bmv[k]; raw += bmv[k] * bv[k]; }
        if (cnt == 0.f) cnt = 1.f;
        val = m * (u + wpu[s] * (raw / cnt));   // weighted_unaries
        key = (s == tgt) ? INFINITY : val;      // target -> +inf
    }

    // rank = #states with strictly greater key, ties by lower index
    int rank = 0;
    #pragma unroll
    for (int t = 0; t < SS; ++t) {
        float kt = __shfl(key, t, 64);
        rank += (kt > key) || (kt == key && t < lane);
    }
    bool sel = (lane < SS) && (rank < KK);

    if (beam16) {
        // target -> slot 0; remaining selected states sorted by state index.
        // Valid: only slot 0 is semantically special (pair (0,0) gold); the
        // logsumexp is set-invariant. Sorted order = ascending gather addrs.
        bool sel_nt = sel && (lane != tgt);
        unsigned long long bal = __ballot(sel_nt);
        if (sel) {
            int slot = (lane == tgt) ? 0
                       : 1 + __popcll(bal & ((1ull << lane) - 1ull));
            beam16[slot] = lane;
        }
    }

    if (gold_out) {
        float mv = sel ? val : -INFINITY;
        #pragma unroll
        for (int off = 32; off >= 1; off >>= 1)
            mv = fmaxf(mv, __shfl_xor(mv, off, 64));
        float se = sel ? expf(val - mv) : 0.f;
        #pragma unroll
        for (int off = 32; off >= 1; off >>= 1)
            se += __shfl_xor(se, off, 64);
        float vt = __shfl(val, tgt, 64);
        if (lane == 0)
            *gold_out = (m > 0.f) ? (vt - mv - logf(se)) : 0.f;
    }
}

// ---------------- Kernel 1: edges + node golds (2048 x 256, no fences) -------
// Per block (one edge): wave0 -> n1 beam, wave1 -> n2 beam, wave2 -> node gold
// (blocks 0..191). Then all 256 threads gather one beam pair each with
// on-the-fly imask/wpb fold (no cbin table). R4 lesson: keep 256-thread
// blocks (32 waves/CU). R1/R5 lesson: no cross-block protocol.
__global__ __launch_bounds__(256) void main_kernel(
    const float* __restrict__ unaries,
    const float* __restrict__ behaviors,
    const float* __restrict__ interactions,
    const float* __restrict__ wpu,
    const float* __restrict__ wpb,
    const void* masks, const void* bmask, const void* imask,
    const int* __restrict__ edges, const void* binmask,
    const int* __restrict__ targets,
    float* __restrict__ node_gold,
    float* __restrict__ edge_gold)
{
    int be = blockIdx.x;            // be = b*E + e
    int b = be >> 9;                // /EE
    int tid = threadIdx.x;
    int wid = tid >> 6, lane = tid & 63;
    int flag = detect_flag(bmask, lane);

    int2 e2 = ((const int2*)edges)[be];
    int n1 = e2.x, n2 = e2.y;

    __shared__ int beamA[KK], beamB[KK];

    // phase 1: beams (waves 0,1) + node gold (wave 2, blocks 0..191)
    bool active = (wid < 2) || (wid == 2 && be < NNODE);
    if (active) {
        int node = (wid == 0) ? (b * NN + n1)
                 : (wid == 1) ? (b * NN + n2) : be;
        int* bptr = (wid == 0) ? beamA : (wid == 1) ? beamB : nullptr;
        float* gptr = (wid == 2) ? &node_gold[be] : nullptr;
        node_beam(node, lane, flag, unaries, behaviors, masks, targets,
                  wpu, bmask, bptr, gptr);
    }
    __syncthreads();

    // phase 2: one beam pair per thread
    int i = tid >> 4, j = tid & 15;
    int s1 = beamA[i], s2 = beamB[j];
    int p = s1 * SS + s2;

    size_t base = (((size_t)(b * NN + n1) * NN + n2) * (SS * SS) + p) * AI;
    float4 x0 = *(const float4*)(interactions + base);
    float4 x1 = *(const float4*)(interactions + base + 4);
    float xv[8] = {x0.x,x0.y,x0.z,x0.w, x1.x,x1.y,x1.z,x1.w};

    // on-the-fly interaction-mask decode (wave-uniform flag branch)
    float imv[8];
    if (flag == 1) {
        uint2 v = *(const uint2*)((const unsigned char*)imask + p * 8);
        unsigned int w2[2] = {v.x, v.y};
        #pragma unroll
        for (int k = 0; k < 8; ++k)
            imv[k] = ((w2[k >> 2] >> ((k & 3) * 8)) & 255u) ? 1.f : 0.f;
    } else if (flag == 0) {
        const uint4* ip = (const uint4*)((const int*)imask + p * 8);
        uint4 v0 = ip[0], v1 = ip[1];
        imv[0]=v0.x?1.f:0.f; imv[1]=v0.y?1.f:0.f; imv[2]=v0.z?1.f:0.f; imv[3]=v0.w?1.f:0.f;
        imv[4]=v1.x?1.f:0.f; imv[5]=v1.y?1.f:0.f; imv[6]=v1.z?1.f:0.f; imv[7]=v1.w?1.f:0.f;
    } else {
        const float4* fp = (const float4*)((const float*)imask + p * 8);
        float4 v0 = fp[0], v1 = fp[1];
        imv[0]=v0.x!=0.f?1.f:0.f; imv[1]=v0.y!=0.f?1.f:0.f; imv[2]=v0.z!=0.f?1.f:0.f; imv[3]=v0.w!=0.f?1.f:0.f;
        imv[4]=v1.x!=0.f?1.f:0.f; imv[5]=v1.y!=0.f?1.f:0.f; imv[6]=v1.z!=0.f?1.f:0.f; imv[7]=v1.w!=0.f?1.f:0.f;
    }
    float cnt = 0.f, raw = 0.f;
    #pragma unroll
    for (int k = 0; k < 8; ++k) { cnt += imv[k]; raw += imv[k] * xv[k]; }
    if (cnt == 0.f) cnt = 1.f;
    float phi = wpb[p] * (raw / cnt);           // bin_phis[i][j]

    // per-wave logsumexp partials -> single barrier -> combine
    float mw = phi;
    #pragma unroll
    for (int off = 32; off >= 1; off >>= 1)
        mw = fmaxf(mw, __shfl_xor(mw, off, 64));
    float ew = expf(phi - mw);
    #pragma unroll
    for (int off = 32; off >= 1; off >>= 1)
        ew += __shfl_xor(ew, off, 64);

    __shared__ float2 sred[4];
    if (lane == 0) sred[wid] = make_float2(mw, ew);
    __syncthreads();

    if (tid == 0) {                 // holds phi[0][0] = (target1, target2)
        float2 p0 = sred[0], p1 = sred[1], p2 = sred[2], p3 = sred[3];
        float M = fmaxf(fmaxf(p0.x, p1.x), fmaxf(p2.x, p3.x));
        float S = p0.y * expf(p0.x - M) + p1.y * expf(p1.x - M)
                + p2.y * expf(p2.x - M) + p3.y * expf(p3.x - M);
        float gold = phi - M - logf(S);
        bool bm = read_mask(binmask, be, flag);
        edge_gold[be] = bm ? gold : 0.f;
    }
}

// ---------------- Kernel 2: final reduction -> nll ---------------------------
__global__ __launch_bounds__(256) void final_kernel(
    const void* masks, const void* bmask,
    const float* __restrict__ node_gold,
    const float* __restrict__ edge_gold,
    float* __restrict__ out)
{
    int tid = threadIdx.x;          // 4 waves, wave w = batch b
    int b = tid >> 6;
    int lane = tid & 63;
    int flag = detect_flag(bmask, lane);

    float sum = 0.f, cnt = 0.f;
    if (lane < NN) {
        sum += node_gold[b * NN + lane];
        cnt += read_mask(masks, b * NN + lane, flag) ? 1.f : 0.f;
    }
    for (int e = lane; e < EE; e += 64)
        sum += edge_gold[b * EE + e];

    #pragma unroll
    for (int off = 32; off >= 1; off >>= 1) {
        sum += __shfl_xor(sum, off, 64);
        cnt += __shfl_xor(cnt, off, 64);
    }
    __shared__ float sp[4];
    if (lane == 0) sp[b] = sum / cnt;
    __syncthreads();
    if (tid == 0)
        out[0] = -(sp[0] + sp[1] + sp[2] + sp[3]) * (1.f / BB);
}

extern "C" void kernel_launch(void* const* d_in, const int* in_sizes, int n_in,
                              void* d_out, int out_size, void* d_ws, size_t ws_size,
                              hipStream_t stream) {
    const float* unaries      = (const float*)d_in[0];
    const float* behaviors    = (const float*)d_in[1];
    const float* interactions = (const float*)d_in[2];
    const float* wpu          = (const float*)d_in[3];
    const float* wpb          = (const float*)d_in[4];
    const void*  masks        = d_in[5];
    const void*  bmask        = d_in[6];
    const void*  imask        = d_in[7];
    const int*   edges        = (const int*)d_in[8];
    const void*  binmask      = d_in[9];
    const int*   targets      = (const int*)d_in[10];
    float* out = (float*)d_out;

    char* ws = (char*)d_ws;
    float* node_gold = (float*)(ws + WS_NG);
    float* edge_gold = (float*)(ws + WS_EG);

    main_kernel<<<NEDGE, 256, 0, stream>>>(unaries, behaviors, interactions,
                                           wpu, wpb, masks, bmask, imask,
                                           edges, binmask, targets,
                                           node_gold, edge_gold);
    final_kernel<<<1, 256, 0, stream>>>(masks, bmask, node_gold, edge_gold, out);
}